// Round 5
// baseline (354.006 us; speedup 1.0000x reference)
//
#include <hip/hip_runtime.h>

#define N_NODES 50000
#define N_EDGES 400000
#define DIM 512
#define NPAD 50048      // 391 * 128, zero-padded rows
#define MTILES 391
#define NTILES 4
#define NWG (MTILES * NTILES)   // 1564

typedef short  short8  __attribute__((ext_vector_type(8)));
typedef unsigned short ushort8 __attribute__((ext_vector_type(8)));
typedef unsigned short ushort4v __attribute__((ext_vector_type(4)));
typedef float  f32x4   __attribute__((ext_vector_type(4)));
typedef int    int2v   __attribute__((ext_vector_type(2)));

typedef __attribute__((address_space(1))) const unsigned short gu16;
typedef __attribute__((address_space(3))) unsigned short lu16;

__device__ __forceinline__ unsigned short f2bf(float f) {
    unsigned int u = __float_as_uint(f);
    u += 0x7fffu + ((u >> 16) & 1u);   // RNE
    return (unsigned short)(u >> 16);
}
__device__ __forceinline__ float bf2f(unsigned short h) {
    return __uint_as_float(((unsigned int)h) << 16);
}

// ---------- cast & zero-pad X -> bf16 [NPAD][512] ----------
__global__ __launch_bounds__(256) void cast_x_kernel(const float* __restrict__ x,
                                                     unsigned short* __restrict__ xb) {
    size_t t = (size_t)blockIdx.x * 256 + threadIdx.x;
    size_t base = t * 8;
    int row = (int)(base >> 9);
    ushort8 o;
    if (row < N_NODES) {
        f32x4 a = *(const f32x4*)(x + base);
        f32x4 b = *(const f32x4*)(x + base + 4);
        o[0] = f2bf(a[0]); o[1] = f2bf(a[1]); o[2] = f2bf(a[2]); o[3] = f2bf(a[3]);
        o[4] = f2bf(b[0]); o[5] = f2bf(b[1]); o[6] = f2bf(b[2]); o[7] = f2bf(b[3]);
    } else {
        #pragma unroll
        for (int q = 0; q < 8; ++q) o[q] = 0;
    }
    *(ushort8*)(xb + base) = o;
}

// ---------- merged: transpose/cast W  +  row histogram ----------
__global__ __launch_bounds__(256) void wt_hist_kernel(const float* __restrict__ w,
                                                      unsigned short* __restrict__ wt,
                                                      const int* __restrict__ rows,
                                                      int* __restrict__ counts) {
    int b = blockIdx.x;
    if (b < 1024) {
        int t = b * 256 + threadIdx.x;            // 0 .. 512*512-1
        int n = t >> 9, k = t & 511;
        wt[t] = f2bf(w[k * 512 + n]);             // coalesced writes; W reads L2-cached
    } else {
        int e = (b - 1024) * 256 + threadIdx.x;
        if (e < N_EDGES) atomicAdd(&counts[rows[e]], 1);
    }
}

__global__ __launch_bounds__(512) void scan_blocks_kernel(const int* __restrict__ counts,
                                                          int* __restrict__ tmp,
                                                          int* __restrict__ partials) {
    __shared__ int sm[512];
    int i = blockIdx.x * 512 + threadIdx.x;
    int v = (i < N_NODES) ? counts[i] : 0;
    sm[threadIdx.x] = v;
    __syncthreads();
    #pragma unroll
    for (int off = 1; off < 512; off <<= 1) {
        int val = 0;
        if ((int)threadIdx.x >= off) val = sm[threadIdx.x - off];
        __syncthreads();
        if ((int)threadIdx.x >= off) sm[threadIdx.x] += val;
        __syncthreads();
    }
    if (i < N_NODES) tmp[i] = sm[threadIdx.x] - v;   // exclusive within block
    if (threadIdx.x == 511) partials[blockIdx.x] = sm[511];
}

__global__ __launch_bounds__(128) void scan_partials_kernel(int* __restrict__ partials) {
    __shared__ int sm[128];
    const int nb = 98;
    int v = ((int)threadIdx.x < nb) ? partials[threadIdx.x] : 0;
    sm[threadIdx.x] = v;
    __syncthreads();
    #pragma unroll
    for (int off = 1; off < 128; off <<= 1) {
        int val = 0;
        if ((int)threadIdx.x >= off) val = sm[threadIdx.x - off];
        __syncthreads();
        if ((int)threadIdx.x >= off) sm[threadIdx.x] += val;
        __syncthreads();
    }
    if ((int)threadIdx.x < nb) partials[threadIdx.x] = sm[threadIdx.x] - v;  // exclusive, in place
}

__global__ __launch_bounds__(256) void add_offsets_kernel(const int* __restrict__ tmp,
                                                          const int* __restrict__ partials,
                                                          int* __restrict__ row_start,
                                                          int* __restrict__ cursor) {
    int i = blockIdx.x * 256 + threadIdx.x;
    if (i < N_NODES) {
        int rs = tmp[i] + partials[i >> 9];
        row_start[i] = rs;
        cursor[i] = rs;
    }
}

__global__ __launch_bounds__(256) void scatter_kernel(const int* __restrict__ rows,
                                                      const int* __restrict__ cols,
                                                      const float* __restrict__ vals,
                                                      int* __restrict__ cursor,
                                                      int2v* __restrict__ csr_cv) {
    int e = blockIdx.x * 256 + threadIdx.x;
    if (e < N_EDGES) {
        int r = rows[e];
        int p = atomicAdd(&cursor[r], 1);
        int2v cv;
        cv[0] = cols[e];
        cv[1] = __float_as_int(vals[e]);
        csr_cv[p] = cv;
    }
}

// ---------- bf16 MFMA GEMM: 128x128 tile, BK=64, global_load_lds, XCD swizzle ----------
__global__ __launch_bounds__(256) void gemm_kernel(const unsigned short* __restrict__ Xb,
                                                   const unsigned short* __restrict__ Wt,
                                                   unsigned short* __restrict__ S) {
    __shared__ __align__(16) unsigned short As[128 * 64];
    __shared__ __align__(16) unsigned short Bs[128 * 64];

    // bijective XCD swizzle (m204): all 4 column-blocks of an A-panel -> same XCD
    const int q = NWG / 8, r8 = NWG % 8;               // 195, 4
    int b = blockIdx.x;
    int xcd = b & 7, loc = b >> 3;
    int l = (xcd < r8 ? xcd * (q + 1) : r8 * (q + 1) + (xcd - r8) * q) + loc;
    const int m0 = (l >> 2) * 128;
    const int n0 = (l & 3) * 128;

    const int t = threadIdx.x;
    const int lane = t & 63;
    const int w = t >> 6;
    const int wr = w >> 1, wc = w & 1;          // 2x2 waves, each 64x64
    const int fr = lane & 15;                    // A/B 16-dim index; C col
    const int kg = lane >> 4;                    // k-group (8 contiguous k per lane)

    f32x4 acc[4][4];
    #pragma unroll
    for (int i = 0; i < 4; ++i)
        #pragma unroll
        for (int j = 0; j < 4; ++j)
            #pragma unroll
            for (int qq = 0; qq < 4; ++qq) acc[i][j][qq] = 0.0f;

    // staging map (BK=64, row pitch 128B): call c, wave w, lane l ->
    //   LDS byte L = c*4096 + w*1024 + l*16 ; row = L>>7 = c*32 + w*8 + (l>>3); u16col = (l&7)*8
    const int srow = w * 8 + (lane >> 3);
    const int scol = (lane & 7) * 8;
    const unsigned short* gA = Xb + (size_t)(m0 + srow) * DIM + scol;
    const unsigned short* gB = Wt + (size_t)(n0 + srow) * DIM + scol;
    lu16* AsW = (lu16*)As + w * 512;             // wave-uniform base; +c*2048 per call
    lu16* BsW = (lu16*)Bs + w * 512;

    for (int kk = 0; kk < DIM; kk += 64) {
        #pragma unroll
        for (int c = 0; c < 4; ++c) {
            __builtin_amdgcn_global_load_lds((gu16*)(gA + (size_t)c * 32 * DIM + kk), AsW + c * 2048, 16, 0, 0);
            __builtin_amdgcn_global_load_lds((gu16*)(gB + (size_t)c * 32 * DIM + kk), BsW + c * 2048, 16, 0, 0);
        }
        __syncthreads();

        short8 af[4][2], bf[4][2];
        #pragma unroll
        for (int mi = 0; mi < 4; ++mi)
            #pragma unroll
            for (int ks = 0; ks < 2; ++ks)
                af[mi][ks] = *(const short8*)&As[(wr * 64 + mi * 16 + fr) * 64 + ks * 32 + kg * 8];
        #pragma unroll
        for (int ni = 0; ni < 4; ++ni)
            #pragma unroll
            for (int ks = 0; ks < 2; ++ks)
                bf[ni][ks] = *(const short8*)&Bs[(wc * 64 + ni * 16 + fr) * 64 + ks * 32 + kg * 8];

        #pragma unroll
        for (int ks = 0; ks < 2; ++ks)
            #pragma unroll
            for (int mi = 0; mi < 4; ++mi)
                #pragma unroll
                for (int ni = 0; ni < 4; ++ni)
                    acc[mi][ni] = __builtin_amdgcn_mfma_f32_16x16x32_bf16(af[mi][ks], bf[ni][ks], acc[mi][ni], 0, 0, 0);

        __syncthreads();
    }

    // epilogue: C/D layout col = lane&15, row = (lane>>4)*4 + j  [verified m89/m91]
    #pragma unroll
    for (int mi = 0; mi < 4; ++mi) {
        #pragma unroll
        for (int ni = 0; ni < 4; ++ni) {
            int gr = m0 + wr * 64 + mi * 16 + kg * 4;
            int gc = n0 + wc * 64 + ni * 16 + fr;
            #pragma unroll
            for (int j = 0; j < 4; ++j)
                S[(size_t)(gr + j) * DIM + gc] = f2bf(acc[mi][ni][j]);
        }
    }
}

// ---------- SpMM (D-split): one pass computes dims [d0, d0+256) ----------
// 4 rows/block (1 wave each). Lane owns 4 contiguous dims -> 8B gathers (512B/wave,
// full lines) and ONE f32x4 store per row (1KB/wave contiguous, full lines, no RFO).
__global__ __launch_bounds__(256) void spmm_kernel(const unsigned short* __restrict__ S,
                                                   const int* __restrict__ row_start,
                                                   const int* __restrict__ counts,
                                                   const int2v* __restrict__ cv,
                                                   const float* __restrict__ bias,
                                                   float* __restrict__ out,
                                                   int d0) {
    const int r = blockIdx.x * 4 + (threadIdx.x >> 6);
    const int lane = threadIdx.x & 63;
    const int s = row_start[r];
    const int n = counts[r];
    const int d = d0 + lane * 4;
    const unsigned short* Sd = S + d;

    float a0 = 0.f, a1 = 0.f, a2 = 0.f, a3 = 0.f;

    for (int j = 0; j < n; j += 4) {
        // always load 4 edge records (csr_cv padded by 8); predicate col/val past row end
        int2v e0 = cv[s + j];
        int2v e1 = cv[s + j + 1];
        int2v e2 = cv[s + j + 2];
        int2v e3 = cv[s + j + 3];
        int c0 = e0[0];
        int c1 = (j + 1 < n) ? e1[0] : 0;
        int c2 = (j + 2 < n) ? e2[0] : 0;
        int c3 = (j + 3 < n) ? e3[0] : 0;
        float v0 = __int_as_float(e0[1]);
        float v1 = (j + 1 < n) ? __int_as_float(e1[1]) : 0.0f;
        float v2 = (j + 2 < n) ? __int_as_float(e2[1]) : 0.0f;
        float v3 = (j + 3 < n) ? __int_as_float(e3[1]) : 0.0f;
        // 4 independent 8B gathers in flight
        ushort4v x0 = *(const ushort4v*)&Sd[(size_t)c0 * DIM];
        ushort4v x1 = *(const ushort4v*)&Sd[(size_t)c1 * DIM];
        ushort4v x2 = *(const ushort4v*)&Sd[(size_t)c2 * DIM];
        ushort4v x3 = *(const ushort4v*)&Sd[(size_t)c3 * DIM];
        a0 += v0 * bf2f(x0[0]) + v1 * bf2f(x1[0]) + v2 * bf2f(x2[0]) + v3 * bf2f(x3[0]);
        a1 += v0 * bf2f(x0[1]) + v1 * bf2f(x1[1]) + v2 * bf2f(x2[1]) + v3 * bf2f(x3[1]);
        a2 += v0 * bf2f(x0[2]) + v1 * bf2f(x1[2]) + v2 * bf2f(x2[2]) + v3 * bf2f(x3[2]);
        a3 += v0 * bf2f(x0[3]) + v1 * bf2f(x1[3]) + v2 * bf2f(x2[3]) + v3 * bf2f(x3[3]);
    }

    f32x4 o;
    o[0] = a0 + bias[d];
    o[1] = a1 + bias[d + 1];
    o[2] = a2 + bias[d + 2];
    o[3] = a3 + bias[d + 3];
    *(f32x4*)&out[(size_t)r * DIM + d] = o;   // 64 lanes x 16B = 1KB contiguous, full lines
}

extern "C" void kernel_launch(void* const* d_in, const int* in_sizes, int n_in,
                              void* d_out, int out_size, void* d_ws, size_t ws_size,
                              hipStream_t stream) {
    const float* x    = (const float*)d_in[0];
    const int*   rows = (const int*)d_in[1];
    const int*   cols = (const int*)d_in[2];
    const float* vals = (const float*)d_in[3];
    const float* w    = (const float*)d_in[4];
    const float* bias = (const float*)d_in[5];
    float* out = (float*)d_out;

    char* ws = (char*)d_ws;
    size_t off = 0;
    auto alloc = [&](size_t bytes) -> char* {
        char* p = ws + off;
        off = (off + bytes + 255) & ~(size_t)255;
        return p;
    };
    unsigned short* Xb      = (unsigned short*)alloc((size_t)NPAD * DIM * 2);   // 51.25 MB
    unsigned short* Wt      = (unsigned short*)alloc((size_t)DIM * DIM * 2);    // 0.5 MB
    unsigned short* S       = (unsigned short*)alloc((size_t)NPAD * DIM * 2);   // 51.25 MB
    int*            counts  = (int*)alloc((size_t)N_NODES * 4);
    int*            tmp     = (int*)alloc((size_t)N_NODES * 4);
    int*            rstart  = (int*)alloc((size_t)N_NODES * 4);
    int*            cursor  = (int*)alloc((size_t)N_NODES * 4);
    int*            partials= (int*)alloc(512);
    int2v*          csr_cv  = (int2v*)alloc((size_t)(N_EDGES + 8) * 8);

    hipMemsetAsync(counts, 0, (size_t)N_NODES * 4, stream);

    cast_x_kernel<<<(NPAD * DIM / 8) / 256, 256, 0, stream>>>(x, Xb);
    wt_hist_kernel<<<1024 + (N_EDGES + 255) / 256, 256, 0, stream>>>(w, Wt, rows, counts);

    scan_blocks_kernel<<<98, 512, 0, stream>>>(counts, tmp, partials);
    scan_partials_kernel<<<1, 128, 0, stream>>>(partials);
    add_offsets_kernel<<<(N_NODES + 255) / 256, 256, 0, stream>>>(tmp, partials, rstart, cursor);
    scatter_kernel<<<(N_EDGES + 255) / 256, 256, 0, stream>>>(rows, cols, vals, cursor, csr_cv);

    gemm_kernel<<<NWG, 256, 0, stream>>>(Xb, Wt, S);
    spmm_kernel<<<N_NODES / 4, 256, 0, stream>>>(S, rstart, counts, csr_cv, bias, out, 0);
    spmm_kernel<<<N_NODES / 4, 256, 0, stream>>>(S, rstart, counts, csr_cv, bias, out, 256);
}

// Round 6
// 340.313 us; speedup vs baseline: 1.0402x; 1.0402x over previous
//
#include <hip/hip_runtime.h>

#define N_NODES 50000
#define N_EDGES 400000
#define DIM 512
#define NPAD 50048      // 391 * 128, zero-padded rows
#define MTILES 391
#define NTILES 4
#define NWG (MTILES * NTILES)   // 1564

// prep kernel block ranges
#define PREP_XBLK 12512          // NPAD*DIM/8/256
#define PREP_WBLK 1024           // 512*512/256
#define PREP_HBLK 1563           // ceil(400000/256)

typedef short  short8  __attribute__((ext_vector_type(8)));
typedef unsigned short ushort8 __attribute__((ext_vector_type(8)));
typedef float  f32x4   __attribute__((ext_vector_type(4)));
typedef int    int2v   __attribute__((ext_vector_type(2)));

typedef __attribute__((address_space(1))) const unsigned short gu16;
typedef __attribute__((address_space(3))) unsigned short lu16;

__device__ __forceinline__ unsigned short f2bf(float f) {
    unsigned int u = __float_as_uint(f);
    u += 0x7fffu + ((u >> 16) & 1u);   // RNE
    return (unsigned short)(u >> 16);
}
__device__ __forceinline__ float bf2f(unsigned short h) {
    return __uint_as_float(((unsigned int)h) << 16);
}

// ---------- merged prep: X cast/pad + W transpose/cast + row histogram ----------
__global__ __launch_bounds__(256) void prep_kernel(const float* __restrict__ x,
                                                   unsigned short* __restrict__ xb,
                                                   const float* __restrict__ w,
                                                   unsigned short* __restrict__ wt,
                                                   const int* __restrict__ rows,
                                                   int* __restrict__ counts) {
    int b = blockIdx.x;
    if (b < PREP_XBLK) {
        size_t t = (size_t)b * 256 + threadIdx.x;
        size_t base = t * 8;
        int row = (int)(base >> 9);
        ushort8 o;
        if (row < N_NODES) {
            f32x4 a = *(const f32x4*)(x + base);
            f32x4 c = *(const f32x4*)(x + base + 4);
            o[0] = f2bf(a[0]); o[1] = f2bf(a[1]); o[2] = f2bf(a[2]); o[3] = f2bf(a[3]);
            o[4] = f2bf(c[0]); o[5] = f2bf(c[1]); o[6] = f2bf(c[2]); o[7] = f2bf(c[3]);
        } else {
            #pragma unroll
            for (int q = 0; q < 8; ++q) o[q] = 0;
        }
        *(ushort8*)(xb + base) = o;
    } else if (b < PREP_XBLK + PREP_WBLK) {
        int t = (b - PREP_XBLK) * 256 + threadIdx.x;   // 0 .. 512*512-1
        int n = t >> 9, k = t & 511;
        wt[t] = f2bf(w[k * 512 + n]);                  // coalesced writes
    } else {
        int e = (b - PREP_XBLK - PREP_WBLK) * 256 + threadIdx.x;
        if (e < N_EDGES) atomicAdd(&counts[rows[e]], 1);
    }
}

// ---------- scan of counts within 512-blocks; partials = raw block sums ----------
__global__ __launch_bounds__(512) void scan_blocks_kernel(const int* __restrict__ counts,
                                                          int* __restrict__ tmp,
                                                          int* __restrict__ partials) {
    __shared__ int sm[512];
    int i = blockIdx.x * 512 + threadIdx.x;
    int v = (i < N_NODES) ? counts[i] : 0;
    sm[threadIdx.x] = v;
    __syncthreads();
    #pragma unroll
    for (int off = 1; off < 512; off <<= 1) {
        int val = 0;
        if ((int)threadIdx.x >= off) val = sm[threadIdx.x - off];
        __syncthreads();
        if ((int)threadIdx.x >= off) sm[threadIdx.x] += val;
        __syncthreads();
    }
    if (i < N_NODES) tmp[i] = sm[threadIdx.x] - v;   // exclusive within block
    if (threadIdx.x == 511) partials[blockIdx.x] = sm[511];
}

// ---------- add block offsets; every block redundantly scans the 98 partials ----------
__global__ __launch_bounds__(256) void add_offsets_kernel(const int* __restrict__ tmp,
                                                          const int* __restrict__ partials,
                                                          int* __restrict__ row_start,
                                                          int* __restrict__ cursor) {
    __shared__ int pin[128], pinc[128];
    const int tid = threadIdx.x;
    const int nb = 98;
    if (tid < 128) {
        int v = (tid < nb) ? partials[tid] : 0;
        pin[tid] = v;
        pinc[tid] = v;
    }
    __syncthreads();
    #pragma unroll
    for (int off = 1; off < 128; off <<= 1) {
        int val = 0;
        if (tid < 128 && tid >= off) val = pinc[tid - off];
        __syncthreads();
        if (tid < 128 && tid >= off) pinc[tid] += val;
        __syncthreads();
    }
    int i = blockIdx.x * 256 + tid;
    if (i < N_NODES) {
        int b9 = i >> 9;
        int excl = pinc[b9] - pin[b9];
        int rs = tmp[i] + excl;
        row_start[i] = rs;
        cursor[i] = rs;
    }
}

__global__ __launch_bounds__(256) void scatter_kernel(const int* __restrict__ rows,
                                                      const int* __restrict__ cols,
                                                      const float* __restrict__ vals,
                                                      int* __restrict__ cursor,
                                                      int2v* __restrict__ csr_cv) {
    int e = blockIdx.x * 256 + threadIdx.x;
    if (e < N_EDGES) {
        int r = rows[e];
        int p = atomicAdd(&cursor[r], 1);
        int2v cv;
        cv[0] = cols[e];
        cv[1] = __float_as_int(vals[e]);
        csr_cv[p] = cv;
    }
}

// ---------- bf16 MFMA GEMM: 128x128 tile, BK=64, global_load_lds, XCD swizzle ----------
__global__ __launch_bounds__(256) void gemm_kernel(const unsigned short* __restrict__ Xb,
                                                   const unsigned short* __restrict__ Wt,
                                                   unsigned short* __restrict__ S) {
    __shared__ __align__(16) unsigned short As[128 * 64];
    __shared__ __align__(16) unsigned short Bs[128 * 64];

    // bijective XCD swizzle (m204): all 4 column-blocks of an A-panel -> same XCD
    const int q = NWG / 8, r8 = NWG % 8;               // 195, 4
    int b = blockIdx.x;
    int xcd = b & 7, loc = b >> 3;
    int l = (xcd < r8 ? xcd * (q + 1) : r8 * (q + 1) + (xcd - r8) * q) + loc;
    const int m0 = (l >> 2) * 128;
    const int n0 = (l & 3) * 128;

    const int t = threadIdx.x;
    const int lane = t & 63;
    const int w = t >> 6;
    const int wr = w >> 1, wc = w & 1;          // 2x2 waves, each 64x64
    const int fr = lane & 15;                    // A/B 16-dim index; C col
    const int kg = lane >> 4;                    // k-group (8 contiguous k per lane)

    f32x4 acc[4][4];
    #pragma unroll
    for (int i = 0; i < 4; ++i)
        #pragma unroll
        for (int j = 0; j < 4; ++j)
            #pragma unroll
            for (int qq = 0; qq < 4; ++qq) acc[i][j][qq] = 0.0f;

    // staging map (BK=64, row pitch 128B): call c, wave w, lane l ->
    //   LDS byte L = c*4096 + w*1024 + l*16 ; row = L>>7 = c*32 + w*8 + (l>>3); u16col = (l&7)*8
    const int srow = w * 8 + (lane >> 3);
    const int scol = (lane & 7) * 8;
    const unsigned short* gA = Xb + (size_t)(m0 + srow) * DIM + scol;
    const unsigned short* gB = Wt + (size_t)(n0 + srow) * DIM + scol;
    lu16* AsW = (lu16*)As + w * 512;             // wave-uniform base; +c*2048 per call
    lu16* BsW = (lu16*)Bs + w * 512;

    for (int kk = 0; kk < DIM; kk += 64) {
        #pragma unroll
        for (int c = 0; c < 4; ++c) {
            __builtin_amdgcn_global_load_lds((gu16*)(gA + (size_t)c * 32 * DIM + kk), AsW + c * 2048, 16, 0, 0);
            __builtin_amdgcn_global_load_lds((gu16*)(gB + (size_t)c * 32 * DIM + kk), BsW + c * 2048, 16, 0, 0);
        }
        __syncthreads();

        short8 af[4][2], bf[4][2];
        #pragma unroll
        for (int mi = 0; mi < 4; ++mi)
            #pragma unroll
            for (int ks = 0; ks < 2; ++ks)
                af[mi][ks] = *(const short8*)&As[(wr * 64 + mi * 16 + fr) * 64 + ks * 32 + kg * 8];
        #pragma unroll
        for (int ni = 0; ni < 4; ++ni)
            #pragma unroll
            for (int ks = 0; ks < 2; ++ks)
                bf[ni][ks] = *(const short8*)&Bs[(wc * 64 + ni * 16 + fr) * 64 + ks * 32 + kg * 8];

        #pragma unroll
        for (int ks = 0; ks < 2; ++ks)
            #pragma unroll
            for (int mi = 0; mi < 4; ++mi)
                #pragma unroll
                for (int ni = 0; ni < 4; ++ni)
                    acc[mi][ni] = __builtin_amdgcn_mfma_f32_16x16x32_bf16(af[mi][ks], bf[ni][ks], acc[mi][ni], 0, 0, 0);

        __syncthreads();
    }

    // epilogue: C/D layout col = lane&15, row = (lane>>4)*4 + j  [verified m89/m91]
    #pragma unroll
    for (int mi = 0; mi < 4; ++mi) {
        #pragma unroll
        for (int ni = 0; ni < 4; ++ni) {
            int gr = m0 + wr * 64 + mi * 16 + kg * 4;
            int gc = n0 + wc * 64 + ni * 16 + fr;
            #pragma unroll
            for (int j = 0; j < 4; ++j)
                S[(size_t)(gr + j) * DIM + gc] = f2bf(acc[mi][ni][j]);
        }
    }
}

// ---------- SpMM: 4 rows/block (1 wave each), 8-deep predicated gather batches ----------
// single-pass 16B/lane gathers (R4 best); 8 independent edge->gather chains in flight.
__global__ __launch_bounds__(256) void spmm_kernel(const unsigned short* __restrict__ S,
                                                   const int* __restrict__ row_start,
                                                   const int* __restrict__ counts,
                                                   const int2v* __restrict__ cv,
                                                   const float* __restrict__ bias,
                                                   float* __restrict__ out) {
    const int r = blockIdx.x * 4 + (threadIdx.x >> 6);
    const int lane = threadIdx.x & 63;
    const int s = row_start[r];
    const int n = counts[r];
    const size_t lo = (size_t)lane * 8;

    float acc[8];
    #pragma unroll
    for (int q = 0; q < 8; ++q) acc[q] = 0.0f;

    for (int j = 0; j < n; j += 8) {
        int   cc[8];
        float vv[8];
        #pragma unroll
        for (int k = 0; k < 8; ++k) {
            int2v e = cv[s + j + k];            // csr_cv padded by 8; poison masked below
            bool ok = (j + k < n);
            cc[k] = ok ? e[0] : 0;
            vv[k] = ok ? __int_as_float(e[1]) : 0.0f;
        }
        ushort8 xv[8];
        #pragma unroll
        for (int k = 0; k < 8; ++k)
            xv[k] = *(const ushort8*)&S[(size_t)cc[k] * DIM + lo];
        #pragma unroll
        for (int k = 0; k < 8; ++k)
            #pragma unroll
            for (int q = 0; q < 8; ++q)
                acc[q] += vv[k] * bf2f(xv[k][q]);
    }

    #pragma unroll
    for (int q = 0; q < 8; ++q) acc[q] += bias[lane * 8 + q];

    f32x4 o0, o1;
    #pragma unroll
    for (int q = 0; q < 4; ++q) { o0[q] = acc[q]; o1[q] = acc[4 + q]; }
    *(f32x4*)&out[(size_t)r * DIM + lo] = o0;          // cached stores (nt regressed: R3)
    *(f32x4*)&out[(size_t)r * DIM + lo + 4] = o1;
}

extern "C" void kernel_launch(void* const* d_in, const int* in_sizes, int n_in,
                              void* d_out, int out_size, void* d_ws, size_t ws_size,
                              hipStream_t stream) {
    const float* x    = (const float*)d_in[0];
    const int*   rows = (const int*)d_in[1];
    const int*   cols = (const int*)d_in[2];
    const float* vals = (const float*)d_in[3];
    const float* w    = (const float*)d_in[4];
    const float* bias = (const float*)d_in[5];
    float* out = (float*)d_out;

    char* ws = (char*)d_ws;
    size_t off = 0;
    auto alloc = [&](size_t bytes) -> char* {
        char* p = ws + off;
        off = (off + bytes + 255) & ~(size_t)255;
        return p;
    };
    unsigned short* Xb      = (unsigned short*)alloc((size_t)NPAD * DIM * 2);   // 51.25 MB
    unsigned short* Wt      = (unsigned short*)alloc((size_t)DIM * DIM * 2);    // 0.5 MB
    unsigned short* S       = (unsigned short*)alloc((size_t)NPAD * DIM * 2);   // 51.25 MB
    int*            counts  = (int*)alloc((size_t)N_NODES * 4);
    int*            tmp     = (int*)alloc((size_t)N_NODES * 4);
    int*            rstart  = (int*)alloc((size_t)N_NODES * 4);
    int*            cursor  = (int*)alloc((size_t)N_NODES * 4);
    int*            partials= (int*)alloc(512);
    int2v*          csr_cv  = (int2v*)alloc((size_t)(N_EDGES + 8) * 8);

    hipMemsetAsync(counts, 0, (size_t)N_NODES * 4, stream);

    prep_kernel<<<PREP_XBLK + PREP_WBLK + PREP_HBLK, 256, 0, stream>>>(x, Xb, w, Wt, rows, counts);
    scan_blocks_kernel<<<98, 512, 0, stream>>>(counts, tmp, partials);
    add_offsets_kernel<<<(N_NODES + 255) / 256, 256, 0, stream>>>(tmp, partials, rstart, cursor);
    scatter_kernel<<<(N_EDGES + 255) / 256, 256, 0, stream>>>(rows, cols, vals, cursor, csr_cv);

    gemm_kernel<<<NWG, 256, 0, stream>>>(Xb, Wt, S);
    spmm_kernel<<<N_NODES / 4, 256, 0, stream>>>(S, rstart, counts, csr_cv, bias, out);
}

// Round 7
// 335.094 us; speedup vs baseline: 1.0564x; 1.0156x over previous
//
#include <hip/hip_runtime.h>

#define N_NODES 50000
#define N_EDGES 400000
#define DIM 512
#define NPAD 50048      // 391 * 128, zero-padded rows
#define MTILES 391
#define NTILES 4
#define NWG (MTILES * NTILES)   // 1564
#define SCAT_BLK 1563           // ceil(400000/256) scatter blocks fused into gemm

// prep kernel block ranges
#define PREP_XBLK 12512          // NPAD*DIM/8/256
#define PREP_WBLK 1024           // 512*512/256
#define PREP_HBLK 1563           // ceil(400000/256)

typedef short  short8  __attribute__((ext_vector_type(8)));
typedef unsigned short ushort8 __attribute__((ext_vector_type(8)));
typedef float  f32x4   __attribute__((ext_vector_type(4)));
typedef int    int2v   __attribute__((ext_vector_type(2)));

typedef __attribute__((address_space(1))) const unsigned short gu16;
typedef __attribute__((address_space(3))) unsigned short lu16;

__device__ __forceinline__ unsigned short f2bf(float f) {
    unsigned int u = __float_as_uint(f);
    u += 0x7fffu + ((u >> 16) & 1u);   // RNE
    return (unsigned short)(u >> 16);
}
__device__ __forceinline__ float bf2f(unsigned short h) {
    return __uint_as_float(((unsigned int)h) << 16);
}

// ---------- merged prep: X cast/pad + W transpose/cast + row histogram ----------
__global__ __launch_bounds__(256) void prep_kernel(const float* __restrict__ x,
                                                   unsigned short* __restrict__ xb,
                                                   const float* __restrict__ w,
                                                   unsigned short* __restrict__ wt,
                                                   const int* __restrict__ rows,
                                                   int* __restrict__ counts) {
    int b = blockIdx.x;
    if (b < PREP_XBLK) {
        size_t t = (size_t)b * 256 + threadIdx.x;
        size_t base = t * 8;
        int row = (int)(base >> 9);
        ushort8 o;
        if (row < N_NODES) {
            f32x4 a = *(const f32x4*)(x + base);
            f32x4 c = *(const f32x4*)(x + base + 4);
            o[0] = f2bf(a[0]); o[1] = f2bf(a[1]); o[2] = f2bf(a[2]); o[3] = f2bf(a[3]);
            o[4] = f2bf(c[0]); o[5] = f2bf(c[1]); o[6] = f2bf(c[2]); o[7] = f2bf(c[3]);
        } else {
            #pragma unroll
            for (int q = 0; q < 8; ++q) o[q] = 0;
        }
        *(ushort8*)(xb + base) = o;
    } else if (b < PREP_XBLK + PREP_WBLK) {
        int t = (b - PREP_XBLK) * 256 + threadIdx.x;   // 0 .. 512*512-1
        int n = t >> 9, k = t & 511;
        wt[t] = f2bf(w[k * 512 + n]);                  // coalesced writes
    } else {
        int e = (b - PREP_XBLK - PREP_WBLK) * 256 + threadIdx.x;
        if (e < N_EDGES) atomicAdd(&counts[rows[e]], 1);
    }
}

// ---------- scan of counts within 512-blocks; partials = raw block sums ----------
__global__ __launch_bounds__(512) void scan_blocks_kernel(const int* __restrict__ counts,
                                                          int* __restrict__ tmp,
                                                          int* __restrict__ partials) {
    __shared__ int sm[512];
    int i = blockIdx.x * 512 + threadIdx.x;
    int v = (i < N_NODES) ? counts[i] : 0;
    sm[threadIdx.x] = v;
    __syncthreads();
    #pragma unroll
    for (int off = 1; off < 512; off <<= 1) {
        int val = 0;
        if ((int)threadIdx.x >= off) val = sm[threadIdx.x - off];
        __syncthreads();
        if ((int)threadIdx.x >= off) sm[threadIdx.x] += val;
        __syncthreads();
    }
    if (i < N_NODES) tmp[i] = sm[threadIdx.x] - v;   // exclusive within block
    if (threadIdx.x == 511) partials[blockIdx.x] = sm[511];
}

// ---------- add block offsets; every block redundantly scans the 98 partials ----------
__global__ __launch_bounds__(256) void add_offsets_kernel(const int* __restrict__ tmp,
                                                          const int* __restrict__ partials,
                                                          int* __restrict__ row_start,
                                                          int* __restrict__ cursor) {
    __shared__ int pin[128], pinc[128];
    const int tid = threadIdx.x;
    const int nb = 98;
    if (tid < 128) {
        int v = (tid < nb) ? partials[tid] : 0;
        pin[tid] = v;
        pinc[tid] = v;
    }
    __syncthreads();
    #pragma unroll
    for (int off = 1; off < 128; off <<= 1) {
        int val = 0;
        if (tid < 128 && tid >= off) val = pinc[tid - off];
        __syncthreads();
        if (tid < 128 && tid >= off) pinc[tid] += val;
        __syncthreads();
    }
    int i = blockIdx.x * 256 + tid;
    if (i < N_NODES) {
        int b9 = i >> 9;
        int excl = pinc[b9] - pin[b9];
        int rs = tmp[i] + excl;
        row_start[i] = rs;
        cursor[i] = rs;
    }
}

// ---------- fused: COO->CSR scatter (first SCAT_BLK blocks) + bf16 MFMA GEMM ----------
// Independent halves: scatter writes csr_cv/cursor; gemm reads Xb/Wt, writes S.
// Both only need {prep, scan, add_offsets} done; spmm consumes both afterwards.
__global__ __launch_bounds__(256) void gemm_scatter_kernel(const unsigned short* __restrict__ Xb,
                                                           const unsigned short* __restrict__ Wt,
                                                           unsigned short* __restrict__ S,
                                                           const int* __restrict__ rows,
                                                           const int* __restrict__ cols,
                                                           const float* __restrict__ vals,
                                                           int* __restrict__ cursor,
                                                           int2v* __restrict__ csr_cv) {
    if (blockIdx.x < SCAT_BLK) {
        // ---- scatter half: latency-bound, issues first, drains under gemm compute ----
        int e = blockIdx.x * 256 + threadIdx.x;
        if (e < N_EDGES) {
            int r = rows[e];
            int p = atomicAdd(&cursor[r], 1);
            int2v cv;
            cv[0] = cols[e];
            cv[1] = __float_as_int(vals[e]);
            csr_cv[p] = cv;
        }
        return;
    }

    // ---- gemm half: 128x128 tile, BK=64, global_load_lds, XCD swizzle ----
    __shared__ __align__(16) unsigned short As[128 * 64];
    __shared__ __align__(16) unsigned short Bs[128 * 64];

    // bijective XCD swizzle (m204): all 4 column-blocks of an A-panel -> same XCD
    const int q = NWG / 8, r8 = NWG % 8;               // 195, 4
    int b = blockIdx.x - SCAT_BLK;
    int xcd = b & 7, loc = b >> 3;
    int l = (xcd < r8 ? xcd * (q + 1) : r8 * (q + 1) + (xcd - r8) * q) + loc;
    const int m0 = (l >> 2) * 128;
    const int n0 = (l & 3) * 128;

    const int t = threadIdx.x;
    const int lane = t & 63;
    const int w = t >> 6;
    const int wr = w >> 1, wc = w & 1;          // 2x2 waves, each 64x64
    const int fr = lane & 15;                    // A/B 16-dim index; C col
    const int kg = lane >> 4;                    // k-group (8 contiguous k per lane)

    f32x4 acc[4][4];
    #pragma unroll
    for (int i = 0; i < 4; ++i)
        #pragma unroll
        for (int j = 0; j < 4; ++j)
            #pragma unroll
            for (int qq = 0; qq < 4; ++qq) acc[i][j][qq] = 0.0f;

    // staging map (BK=64, row pitch 128B): call c, wave w, lane l ->
    //   LDS byte L = c*4096 + w*1024 + l*16 ; row = L>>7 = c*32 + w*8 + (l>>3); u16col = (l&7)*8
    const int srow = w * 8 + (lane >> 3);
    const int scol = (lane & 7) * 8;
    const unsigned short* gA = Xb + (size_t)(m0 + srow) * DIM + scol;
    const unsigned short* gB = Wt + (size_t)(n0 + srow) * DIM + scol;
    lu16* AsW = (lu16*)As + w * 512;             // wave-uniform base; +c*2048 per call
    lu16* BsW = (lu16*)Bs + w * 512;

    for (int kk = 0; kk < DIM; kk += 64) {
        #pragma unroll
        for (int c = 0; c < 4; ++c) {
            __builtin_amdgcn_global_load_lds((gu16*)(gA + (size_t)c * 32 * DIM + kk), AsW + c * 2048, 16, 0, 0);
            __builtin_amdgcn_global_load_lds((gu16*)(gB + (size_t)c * 32 * DIM + kk), BsW + c * 2048, 16, 0, 0);
        }
        __syncthreads();

        short8 af[4][2], bf[4][2];
        #pragma unroll
        for (int mi = 0; mi < 4; ++mi)
            #pragma unroll
            for (int ks = 0; ks < 2; ++ks)
                af[mi][ks] = *(const short8*)&As[(wr * 64 + mi * 16 + fr) * 64 + ks * 32 + kg * 8];
        #pragma unroll
        for (int ni = 0; ni < 4; ++ni)
            #pragma unroll
            for (int ks = 0; ks < 2; ++ks)
                bf[ni][ks] = *(const short8*)&Bs[(wc * 64 + ni * 16 + fr) * 64 + ks * 32 + kg * 8];

        #pragma unroll
        for (int ks = 0; ks < 2; ++ks)
            #pragma unroll
            for (int mi = 0; mi < 4; ++mi)
                #pragma unroll
                for (int ni = 0; ni < 4; ++ni)
                    acc[mi][ni] = __builtin_amdgcn_mfma_f32_16x16x32_bf16(af[mi][ks], bf[ni][ks], acc[mi][ni], 0, 0, 0);

        __syncthreads();
    }

    // epilogue: C/D layout col = lane&15, row = (lane>>4)*4 + j  [verified m89/m91]
    #pragma unroll
    for (int mi = 0; mi < 4; ++mi) {
        #pragma unroll
        for (int ni = 0; ni < 4; ++ni) {
            int gr = m0 + wr * 64 + mi * 16 + kg * 4;
            int gc = n0 + wc * 64 + ni * 16 + fr;
            #pragma unroll
            for (int j = 0; j < 4; ++j)
                S[(size_t)(gr + j) * DIM + gc] = f2bf(acc[mi][ni][j]);
        }
    }
}

// ---------- SpMM: 4 rows/block (1 wave each), 4-deep predicated gather batches ----------
// Bound by L2-miss traffic (R4/R6: batch depth 4 vs 8 identical at 70us, FETCH 192MB).
__global__ __launch_bounds__(256) void spmm_kernel(const unsigned short* __restrict__ S,
                                                   const int* __restrict__ row_start,
                                                   const int* __restrict__ counts,
                                                   const int2v* __restrict__ cv,
                                                   const float* __restrict__ bias,
                                                   float* __restrict__ out) {
    const int r = blockIdx.x * 4 + (threadIdx.x >> 6);
    const int lane = threadIdx.x & 63;
    const int s = row_start[r];
    const int n = counts[r];
    const size_t lo = (size_t)lane * 8;

    float acc[8];
    #pragma unroll
    for (int q = 0; q < 8; ++q) acc[q] = 0.0f;

    for (int j = 0; j < n; j += 4) {
        int2v e0 = cv[s + j];
        int2v e1 = cv[s + j + 1];
        int2v e2 = cv[s + j + 2];
        int2v e3 = cv[s + j + 3];
        int c0 = e0[0];
        int c1 = (j + 1 < n) ? e1[0] : 0;
        int c2 = (j + 2 < n) ? e2[0] : 0;
        int c3 = (j + 3 < n) ? e3[0] : 0;
        float v0 = __int_as_float(e0[1]);
        float v1 = (j + 1 < n) ? __int_as_float(e1[1]) : 0.0f;
        float v2 = (j + 2 < n) ? __int_as_float(e2[1]) : 0.0f;
        float v3 = (j + 3 < n) ? __int_as_float(e3[1]) : 0.0f;
        ushort8 x0 = *(const ushort8*)&S[(size_t)c0 * DIM + lo];
        ushort8 x1 = *(const ushort8*)&S[(size_t)c1 * DIM + lo];
        ushort8 x2 = *(const ushort8*)&S[(size_t)c2 * DIM + lo];
        ushort8 x3 = *(const ushort8*)&S[(size_t)c3 * DIM + lo];
        #pragma unroll
        for (int q = 0; q < 8; ++q) {
            acc[q] += v0 * bf2f(x0[q]);
            acc[q] += v1 * bf2f(x1[q]);
            acc[q] += v2 * bf2f(x2[q]);
            acc[q] += v3 * bf2f(x3[q]);
        }
    }

    #pragma unroll
    for (int q = 0; q < 8; ++q) acc[q] += bias[lane * 8 + q];

    f32x4 o0, o1;
    #pragma unroll
    for (int q = 0; q < 4; ++q) { o0[q] = acc[q]; o1[q] = acc[4 + q]; }
    *(f32x4*)&out[(size_t)r * DIM + lo] = o0;          // cached stores (nt regressed: R3)
    *(f32x4*)&out[(size_t)r * DIM + lo + 4] = o1;
}

extern "C" void kernel_launch(void* const* d_in, const int* in_sizes, int n_in,
                              void* d_out, int out_size, void* d_ws, size_t ws_size,
                              hipStream_t stream) {
    const float* x    = (const float*)d_in[0];
    const int*   rows = (const int*)d_in[1];
    const int*   cols = (const int*)d_in[2];
    const float* vals = (const float*)d_in[3];
    const float* w    = (const float*)d_in[4];
    const float* bias = (const float*)d_in[5];
    float* out = (float*)d_out;

    char* ws = (char*)d_ws;
    size_t off = 0;
    auto alloc = [&](size_t bytes) -> char* {
        char* p = ws + off;
        off = (off + bytes + 255) & ~(size_t)255;
        return p;
    };
    unsigned short* Xb      = (unsigned short*)alloc((size_t)NPAD * DIM * 2);   // 51.25 MB
    unsigned short* Wt      = (unsigned short*)alloc((size_t)DIM * DIM * 2);    // 0.5 MB
    unsigned short* S       = (unsigned short*)alloc((size_t)NPAD * DIM * 2);   // 51.25 MB
    int*            counts  = (int*)alloc((size_t)N_NODES * 4);
    int*            tmp     = (int*)alloc((size_t)N_NODES * 4);
    int*            rstart  = (int*)alloc((size_t)N_NODES * 4);
    int*            cursor  = (int*)alloc((size_t)N_NODES * 4);
    int*            partials= (int*)alloc(512);
    int2v*          csr_cv  = (int2v*)alloc((size_t)(N_EDGES + 8) * 8);

    hipMemsetAsync(counts, 0, (size_t)N_NODES * 4, stream);

    prep_kernel<<<PREP_XBLK + PREP_WBLK + PREP_HBLK, 256, 0, stream>>>(x, Xb, w, Wt, rows, counts);
    scan_blocks_kernel<<<98, 512, 0, stream>>>(counts, tmp, partials);
    add_offsets_kernel<<<(N_NODES + 255) / 256, 256, 0, stream>>>(tmp, partials, rstart, cursor);

    gemm_scatter_kernel<<<SCAT_BLK + NWG, 256, 0, stream>>>(Xb, Wt, S,
                                                            rows, cols, vals, cursor, csr_cv);
    spmm_kernel<<<N_NODES / 4, 256, 0, stream>>>(S, rstart, counts, csr_cv, bias, out);
}